// Round 3
// baseline (1692.957 us; speedup 1.0000x reference)
//
#include <hip/hip_runtime.h>

#define N_ROWS   131072
#define KCODES   128
#define DIM      510
#define DC       16          // d-chunk per LDS stage (halved -> 33 KB LDS -> 4 blocks/CU)
#define BROWS    128         // rows per block
#define NCHUNK   32          // ceil(510/16)
#define BUFSZ    (BROWS * DC)   // 2048 dwords per chunk buffer

// c_sq in fp64 (per-code errors shift dist per-code and can flip argmin; make them ~0)
// Also zero-fills the 32-float zero-pad region used as DMA source for the d>=510 tail.
__global__ __launch_bounds__(64) void csq_kernel(const float* __restrict__ cb,
                                                 float* __restrict__ csq,
                                                 float* __restrict__ zpad) {
    int k = blockIdx.x;
    int l = threadIdx.x;
    if (k == 0 && l < 32) zpad[l] = 0.f;
    double s = 0.0;
    for (int d = l; d < DIM; d += 64) {
        double v = (double)cb[k * DIM + d];
        s += v * v;
    }
    for (int m = 32; m > 0; m >>= 1) s += __shfl_down(s, m);
    if (l == 0) csq[k] = (float)s;
}

// global->LDS DMA staging of one chunk (z + cb) into linear, XOR-swizzled buffers.
// Layout: element (row r, dim d) of the chunk lives at dword  r*16 + (d ^ 4*(r&3)).
// DMA writes linearly (wave-uniform LDS base + lane*4B), so the SOURCE address is
// inverse-swizzled per lane (rule 21: linear dest + swizzled source + swizzled read).
// Segment q of wave w covers LDS dwords F = (w*8+q)*64 + lane:
//   r = 32w + 4q + (lane>>4),  d' = lane&15,  true d = d' ^ 4*(r&3),
//   and r&3 == lane>>4 for every q, so the per-lane swizzle is q-independent.
template <bool GUARD>
__device__ __forceinline__ void stage_chunk(const float* __restrict__ z,
                                            const float* __restrict__ cb,
                                            const float* __restrict__ zpad,
                                            float* zbuf, float* cbuf,
                                            long rowBase, int d0,
                                            int wave, int hl, int dl) {
    const int dq = dl ^ (4 * hl);        // swizzled d within chunk (fixed across q)
    const int gd = d0 + dq;
#pragma unroll
    for (int q = 0; q < 8; ++q) {
        const int r = 32 * wave + 4 * q + hl;
        const float* srcz = z + (rowBase + r) * (long)DIM + gd;
        const float* srcc = cb + r * DIM + gd;
        if (GUARD && gd >= DIM) {        // tail chunk: d = 510/511 -> zeros (per-lane select)
            srcz = zpad + dl;
            srcc = zpad + dl;
        }
        float* dstz = zbuf + (wave * 8 + q) * 64;   // wave-uniform base
        float* dstc = cbuf + (wave * 8 + q) * 64;
        __builtin_amdgcn_global_load_lds(
            (const __attribute__((address_space(1))) void*)srcz,
            (__attribute__((address_space(3))) void*)dstz, 4, 0, 0);
        __builtin_amdgcn_global_load_lds(
            (const __attribute__((address_space(1))) void*)srcc,
            (__attribute__((address_space(3))) void*)dstc, 4, 0, 0);
    }
}

__global__ __launch_bounds__(256, 4) void vq_kernel(const float* __restrict__ z,
                                                    const float* __restrict__ cb,
                                                    const float* __restrict__ csq,
                                                    const float* __restrict__ zpad,
                                                    float* __restrict__ out) {
    __shared__ __align__(16) float zs[2][BUFSZ];
    __shared__ __align__(16) float cs[2][BUFSZ];
    __shared__ int kbest[BROWS];

    const int tid  = threadIdx.x;
    const int wave = tid >> 6;           // 0..3
    const int lane = tid & 63;
    const int lr   = lane >> 3;          // 0..7  (row group within wave)
    const int lc   = lane & 7;           // 0..7  (code group within wave)
    const int hl   = lane >> 4;          // staging: row-within-segment (0..3)
    const int dl   = lane & 15;          // staging: dword-in-row (0..15)
    const long rowBase = (long)blockIdx.x * BROWS;

    // rows of this thread:  wave*32 + lr + 8*i   (i = 0..3)
    // codes of this thread: lc + 8*j             (j = 0..15, ascending k for tie-break)
    const int rbase = wave * 32 + lr;
    const int zsw   = 4 * (lr & 3);      // read-side swizzle (r&3 == lr&3 for z rows)
    const int csw   = 4 * (lc & 3);      // read-side swizzle (r&3 == lc&3 for cs rows)

    float acc[4][16];
    float zsq[4];
#pragma unroll
    for (int i = 0; i < 4; ++i) {
        zsq[i] = 0.f;
#pragma unroll
        for (int j = 0; j < 16; ++j) acc[i][j] = 0.f;
    }

    // prologue: DMA chunk 0 into buffer 0
    stage_chunk<false>(z, cb, zpad, zs[0], cs[0], rowBase, 0, wave, hl, dl);
    __syncthreads();   // drains vmcnt -> chunk 0 resident

    for (int ch = 0; ch < NCHUNK; ++ch) {
        const int b = ch & 1;

        // issue-early: DMA chunk ch+1 into the other buffer (no registers held;
        // latency hides under this chunk's compute; drained by the end barrier)
        if (ch + 1 < NCHUNK) {
            if (ch + 1 == NCHUNK - 1)
                stage_chunk<true >(z, cb, zpad, zs[b ^ 1], cs[b ^ 1], rowBase,
                                   (ch + 1) * DC, wave, hl, dl);
            else
                stage_chunk<false>(z, cb, zpad, zs[b ^ 1], cs[b ^ 1], rowBase,
                                   (ch + 1) * DC, wave, hl, dl);
        }

        // compute current chunk from LDS (arithmetic identical to the passing kernel:
        // per (row,code) the fma chain still runs d ascending in x,y,z,w order; a
        // swizzled float4 read returns elements d = dd..dd+3 in order)
        const float* zbuf = zs[b];
        const float* cbuf = cs[b];
#pragma unroll
        for (int dd = 0; dd < DC; dd += 4) {
            float4 zv[4];
#pragma unroll
            for (int i = 0; i < 4; ++i)
                zv[i] = *(const float4*)&zbuf[(rbase + 8 * i) * DC + (dd ^ zsw)];
            // z_sq accumulated with the same chain structure as the dots
#pragma unroll
            for (int i = 0; i < 4; ++i) {
                zsq[i] = fmaf(zv[i].x, zv[i].x, zsq[i]);
                zsq[i] = fmaf(zv[i].y, zv[i].y, zsq[i]);
                zsq[i] = fmaf(zv[i].z, zv[i].z, zsq[i]);
                zsq[i] = fmaf(zv[i].w, zv[i].w, zsq[i]);
            }
#pragma unroll
            for (int j = 0; j < 16; ++j) {
                float4 cv = *(const float4*)&cbuf[(lc + 8 * j) * DC + (dd ^ csw)];
#pragma unroll
                for (int i = 0; i < 4; ++i) {
                    acc[i][j] = fmaf(zv[i].x, cv.x, acc[i][j]);
                    acc[i][j] = fmaf(zv[i].y, cv.y, acc[i][j]);
                    acc[i][j] = fmaf(zv[i].z, cv.z, acc[i][j]);
                    acc[i][j] = fmaf(zv[i].w, cv.w, acc[i][j]);
                }
            }
        }

        __syncthreads();   // single barrier per chunk: drains DMA + releases buffers
    }

    // argmin epilogue — replicate np's rounding sequence:
    //   t = fp32(z_sq - 2*dot)  (2*dot exact);  dist = fp32(t + c_sq)
#pragma unroll
    for (int i = 0; i < 4; ++i) {
        float bd = 3.0e38f;
        int   bk = 0;
#pragma unroll
        for (int j = 0; j < 16; ++j) {
            int k = lc + 8 * j;
            float t    = zsq[i] - 2.0f * acc[i][j];
            float dist = t + csq[k];
            if (dist < bd) { bd = dist; bk = k; }   // strict <: first (lowest k) wins
        }
#pragma unroll
        for (int m = 1; m < 8; m <<= 1) {
            float od = __shfl_xor(bd, m);
            int   ok = __shfl_xor(bk, m);
            if (od < bd || (od == bd && ok < bk)) { bd = od; bk = ok; }
        }
        if (lc == 0) kbest[rbase + 8 * i] = bk;
    }
    __syncthreads();

    // gather: copy winning codebook rows to out (float2, rows are 8B-aligned)
    for (int r = wave; r < BROWS; r += 4) {
        int k = kbest[r];
        const float2* src = (const float2*)(cb + (long)k * DIM);
        float2* dst = (float2*)(out + (rowBase + r) * DIM);
        for (int d2 = lane; d2 < DIM / 2; d2 += 64) dst[d2] = src[d2];
    }
}

extern "C" void kernel_launch(void* const* d_in, const int* in_sizes, int n_in,
                              void* d_out, int out_size, void* d_ws, size_t ws_size,
                              hipStream_t stream) {
    const float* z  = (const float*)d_in[0];
    const float* cb = (const float*)d_in[1];
    float* out  = (float*)d_out;
    float* csq  = (float*)d_ws;             // 128 floats
    float* zpad = (float*)d_ws + KCODES;    // 32 zero floats (DMA tail source)

    csq_kernel<<<KCODES, 64, 0, stream>>>(cb, csq, zpad);
    vq_kernel<<<N_ROWS / BROWS, 256, 0, stream>>>(z, cb, csq, zpad, out);
}

// Round 4
// 1134.040 us; speedup vs baseline: 1.4929x; 1.4929x over previous
//
#include <hip/hip_runtime.h>

#define N_ROWS   131072
#define KCODES   128
#define DIM      510
#define DC       32          // d-chunk per LDS stage
#define BROWS    128         // rows per block
#define NCHUNK   16          // ceil(510/32)
#define CBUF     (KCODES * DC)   // 4096 dwords per codebook chunk buffer

// c_sq in fp64 (per-code errors shift dist per-code and can flip argmin; make them ~0)
// Also zero-fills the 32-float zero-pad region used as DMA source for the d>=510 tail.
__global__ __launch_bounds__(64) void csq_kernel(const float* __restrict__ cb,
                                                 float* __restrict__ csq,
                                                 float* __restrict__ zpad) {
    int k = blockIdx.x;
    int l = threadIdx.x;
    if (k == 0 && l < 32) zpad[l] = 0.f;
    double s = 0.0;
    for (int d = l; d < DIM; d += 64) {
        double v = (double)cb[k * DIM + d];
        s += v * v;
    }
    for (int m = 32; m > 0; m >>= 1) s += __shfl_down(s, m);
    if (l == 0) csq[k] = (float)s;
}

// unaligned-tolerant vector loads (z rows are only 8B-aligned: DIM=510)
__device__ __forceinline__ float4 load_f4(const float* p) {
    float4 v; __builtin_memcpy(&v, p, 16); return v;
}
__device__ __forceinline__ float2 load_f2(const float* p) {
    float2 v; __builtin_memcpy(&v, p, 8); return v;
}

// global->LDS DMA staging of one codebook chunk into a linear, XOR-swizzled buffer.
// Layout: element (code r, dim d) of the chunk lives at dword  r*32 + (d ^ 4*(r&7)).
// DMA writes linearly (wave-uniform LDS base + lane*4B), so the SOURCE address is
// inverse-swizzled per lane (rule 21). Segment q of wave w covers dwords (w*16+q)*64+lane:
//   r = 32w + 2q + (lane>>5),  d' = lane&31,  true d = d' ^ 4*(r&7).
template <bool GUARD>
__device__ __forceinline__ void stage_cb(const float* __restrict__ cb,
                                         const float* __restrict__ zpad,
                                         float* cbuf, int d0,
                                         int wave, int hl, int dl) {
#pragma unroll
    for (int q = 0; q < 16; ++q) {
        const int r  = 32 * wave + 2 * q + hl;
        const int dq = dl ^ (4 * (r & 7));
        const int gd = d0 + dq;
        const float* srcc = cb + r * DIM + gd;
        if (GUARD && gd >= DIM)          // tail chunk: d = 510/511 -> zeros
            srcc = zpad + dl;
        float* dstc = cbuf + (wave * 16 + q) * 64;   // wave-uniform base
        __builtin_amdgcn_global_load_lds(
            (const __attribute__((address_space(1))) void*)srcc,
            (__attribute__((address_space(3))) void*)dstc, 4, 0, 0);
    }
}

// One chunk of the distance accumulation. z comes straight from global (per-row
// broadcast across the 8 lanes sharing lr; lines consumed contiguously -> L1-hit).
// TAIL: last chunk's dd=28 covers d=508..511 -> float2 + exact zeros (fma identity).
template <bool TAIL>
__device__ __forceinline__ void compute_chunk(const float* __restrict__ z,
                                              const float* __restrict__ cbuf,
                                              const long* zbase, int d0,
                                              int lc, int csw,
                                              float acc[4][16], float zsq[4]) {
#pragma unroll
    for (int dd = 0; dd < DC; dd += 4) {
        float4 zv[4];
        if (TAIL && dd == DC - 4) {
#pragma unroll
            for (int i = 0; i < 4; ++i) {
                float2 t = load_f2(z + zbase[i] + d0 + dd);
                zv[i] = make_float4(t.x, t.y, 0.f, 0.f);
            }
        } else {
#pragma unroll
            for (int i = 0; i < 4; ++i)
                zv[i] = load_f4(z + zbase[i] + d0 + dd);
        }
        // z_sq accumulated with the same chain structure as the dots
#pragma unroll
        for (int i = 0; i < 4; ++i) {
            zsq[i] = fmaf(zv[i].x, zv[i].x, zsq[i]);
            zsq[i] = fmaf(zv[i].y, zv[i].y, zsq[i]);
            zsq[i] = fmaf(zv[i].z, zv[i].z, zsq[i]);
            zsq[i] = fmaf(zv[i].w, zv[i].w, zsq[i]);
        }
#pragma unroll
        for (int j = 0; j < 16; ++j) {
            float4 cv = *(const float4*)&cbuf[(lc + 8 * j) * DC + (dd ^ csw)];
#pragma unroll
            for (int i = 0; i < 4; ++i) {
                acc[i][j] = fmaf(zv[i].x, cv.x, acc[i][j]);
                acc[i][j] = fmaf(zv[i].y, cv.y, acc[i][j]);
                acc[i][j] = fmaf(zv[i].z, cv.z, acc[i][j]);
                acc[i][j] = fmaf(zv[i].w, cv.w, acc[i][j]);
            }
        }
    }
}

__global__ __launch_bounds__(256, 2) void vq_kernel(const float* __restrict__ z,
                                                    const float* __restrict__ cb,
                                                    const float* __restrict__ csq,
                                                    const float* __restrict__ zpad,
                                                    float* __restrict__ out) {
    __shared__ __align__(16) float cs[2][CBUF];   // 32 KB total -> 4 blocks/CU
    __shared__ int kbest[BROWS];

    const int tid  = threadIdx.x;
    const int wave = tid >> 6;           // 0..3
    const int lane = tid & 63;
    const int lr   = lane >> 3;          // 0..7  (row group within wave)
    const int lc   = lane & 7;           // 0..7  (code group within wave)
    const int hl   = lane >> 5;          // staging: half-of-wave
    const int dl   = lane & 31;          // staging: dword-in-segment
    const long rowBase = (long)blockIdx.x * BROWS;

    // rows of this thread:  wave*32 + lr + 8*i   (i = 0..3)
    // codes of this thread: lc + 8*j             (j = 0..15, ascending k for tie-break)
    const int rbase = wave * 32 + lr;
    const int csw   = 4 * lc;            // read-side swizzle (r&7 == lc for cs rows)

    long zbase[4];
#pragma unroll
    for (int i = 0; i < 4; ++i)
        zbase[i] = (rowBase + rbase + 8 * i) * (long)DIM;

    float acc[4][16];
    float zsq[4];
#pragma unroll
    for (int i = 0; i < 4; ++i) {
        zsq[i] = 0.f;
#pragma unroll
        for (int j = 0; j < 16; ++j) acc[i][j] = 0.f;
    }

    // prologue: DMA codebook chunk 0 into buffer 0
    stage_cb<false>(cb, zpad, cs[0], 0, wave, hl, dl);
    __syncthreads();   // drains vmcnt -> chunk 0 resident

    for (int ch = 0; ch < NCHUNK; ++ch) {
        const int b = ch & 1;

        // issue-early: DMA codebook chunk ch+1 into the other buffer (no registers
        // held; latency hides under this chunk's compute; drained by the end barrier)
        if (ch + 1 < NCHUNK) {
            if (ch + 1 == NCHUNK - 1)
                stage_cb<true >(cb, zpad, cs[b ^ 1], (ch + 1) * DC, wave, hl, dl);
            else
                stage_cb<false>(cb, zpad, cs[b ^ 1], (ch + 1) * DC, wave, hl, dl);
        }

        // compute (arithmetic bit-identical to the passing round-2 kernel: same
        // chunk/dd/xyzw chain order; tail adds exact zeros = fma identity)
        if (ch == NCHUNK - 1)
            compute_chunk<true >(z, cs[b], zbase, ch * DC, lc, csw, acc, zsq);
        else
            compute_chunk<false>(z, cs[b], zbase, ch * DC, lc, csw, acc, zsq);

        __syncthreads();   // single barrier per chunk: drains DMA + releases buffer
    }

    // argmin epilogue — replicate np's rounding sequence:
    //   t = fp32(z_sq - 2*dot)  (2*dot exact);  dist = fp32(t + c_sq)
#pragma unroll
    for (int i = 0; i < 4; ++i) {
        float bd = 3.0e38f;
        int   bk = 0;
#pragma unroll
        for (int j = 0; j < 16; ++j) {
            int k = lc + 8 * j;
            float t    = zsq[i] - 2.0f * acc[i][j];
            float dist = t + csq[k];
            if (dist < bd) { bd = dist; bk = k; }   // strict <: first (lowest k) wins
        }
#pragma unroll
        for (int m = 1; m < 8; m <<= 1) {
            float od = __shfl_xor(bd, m);
            int   ok = __shfl_xor(bk, m);
            if (od < bd || (od == bd && ok < bk)) { bd = od; bk = ok; }
        }
        if (lc == 0) kbest[rbase + 8 * i] = bk;
    }
    __syncthreads();

    // gather: copy winning codebook rows to out (float2, rows are 8B-aligned)
    for (int r = wave; r < BROWS; r += 4) {
        int k = kbest[r];
        const float2* src = (const float2*)(cb + (long)k * DIM);
        float2* dst = (float2*)(out + (rowBase + r) * DIM);
        for (int d2 = lane; d2 < DIM / 2; d2 += 64) dst[d2] = src[d2];
    }
}

extern "C" void kernel_launch(void* const* d_in, const int* in_sizes, int n_in,
                              void* d_out, int out_size, void* d_ws, size_t ws_size,
                              hipStream_t stream) {
    const float* z  = (const float*)d_in[0];
    const float* cb = (const float*)d_in[1];
    float* out  = (float*)d_out;
    float* csq  = (float*)d_ws;             // 128 floats
    float* zpad = (float*)d_ws + KCODES;    // 32 zero floats (DMA tail source)

    csq_kernel<<<KCODES, 64, 0, stream>>>(cb, csq, zpad);
    vq_kernel<<<N_ROWS / BROWS, 256, 0, stream>>>(z, cb, csq, zpad, out);
}

// Round 5
// 675.660 us; speedup vs baseline: 2.5056x; 1.6784x over previous
//
#include <hip/hip_runtime.h>

#define N_ROWS   131072
#define KCODES   128
#define DIM      510
#define DC       16          // d-chunk per LDS stage (33 KB total LDS -> 4 blocks/CU)
#define BROWS    128         // rows per block
#define NCHUNK   32          // ceil(510/16)
#define BUFSZ    (BROWS * DC)   // 2048 dwords per chunk buffer

// c_sq in fp64 (per-code errors shift dist per-code and can flip argmin; make them ~0)
// Also zero-fills the 32-float zero-pad region used as DMA source for the d>=510 tail.
__global__ __launch_bounds__(64) void csq_kernel(const float* __restrict__ cb,
                                                 float* __restrict__ csq,
                                                 float* __restrict__ zpad) {
    int k = blockIdx.x;
    int l = threadIdx.x;
    if (k == 0 && l < 32) zpad[l] = 0.f;
    double s = 0.0;
    for (int d = l; d < DIM; d += 64) {
        double v = (double)cb[k * DIM + d];
        s += v * v;
    }
    for (int m = 32; m > 0; m >>= 1) s += __shfl_down(s, m);
    if (l == 0) csq[k] = (float)s;
}

// global->LDS DMA staging of one chunk into linear, XOR-swizzled buffers.
// Layout: element (row r, dim d) lives at dword  r*16 + (d ^ 4*((r>>1)&3)).
// (Key on r>>1: at stride 16, rows r and r+2 alias the same banks; this swizzle
//  puts the 8 rows of one read instr on 8 disjoint bank-quads = all 32 banks.)
// DMA writes linearly (wave-uniform base + lane*4B), so the SOURCE is inverse-
// swizzled per lane (rule 21). Segment q of wave w covers dwords (w*8+q)*64+lane:
//   r = 32w + 4q + (lane>>4),  d' = lane&15,  true d = d' ^ 4*((2q + (lane>>5... )) )
//   with (r>>1)&3 = (2q + ((lane>>4)>>1)) & 3  (16w vanishes mod 4).
template <bool GUARD>
__device__ __forceinline__ void stage_chunk(const float* __restrict__ z,
                                            const float* __restrict__ cb,
                                            const float* __restrict__ zpad,
                                            float* zbuf, float* cbuf,
                                            long rowBase, int d0,
                                            int wave, int h4, int dl) {
#pragma unroll
    for (int q = 0; q < 8; ++q) {
        const int r  = 32 * wave + 4 * q + h4;
        const int sw = 4 * ((2 * q + (h4 >> 1)) & 3);   // == 4*((r>>1)&3)
        const int gd = d0 + (dl ^ sw);
        const float* srcz = z + (rowBase + r) * (long)DIM + gd;
        const float* srcc = cb + r * DIM + gd;
        if (GUARD && gd >= DIM) {        // tail chunk: d = 510/511 -> zeros (per-lane)
            srcz = zpad + dl;
            srcc = zpad + dl;
        }
        float* dstz = zbuf + (wave * 8 + q) * 64;   // wave-uniform base
        float* dstc = cbuf + (wave * 8 + q) * 64;
        __builtin_amdgcn_global_load_lds(
            (const __attribute__((address_space(1))) void*)srcz,
            (__attribute__((address_space(3))) void*)dstz, 4, 0, 0);
        __builtin_amdgcn_global_load_lds(
            (const __attribute__((address_space(1))) void*)srcc,
            (__attribute__((address_space(3))) void*)dstc, 4, 0, 0);
    }
}

__global__ __launch_bounds__(256, 2) void vq_kernel(const float* __restrict__ z,
                                                    const float* __restrict__ cb,
                                                    const float* __restrict__ csq,
                                                    const float* __restrict__ zpad,
                                                    float* __restrict__ out) {
    __shared__ __align__(16) float zs[2][BUFSZ];   // 16 KB
    __shared__ __align__(16) float cs[2][BUFSZ];   // 16 KB
    __shared__ int kbest[BROWS];

    const int tid  = threadIdx.x;
    const int wave = tid >> 6;           // 0..3
    const int lane = tid & 63;
    const int lr   = lane >> 3;          // 0..7  (row group within wave)
    const int lc   = lane & 7;           // 0..7  (code group within wave)
    const int h4   = lane >> 4;          // staging: row-within-segment (0..3)
    const int dl   = lane & 15;          // staging: dword-in-row (0..15)
    const long rowBase = (long)blockIdx.x * BROWS;

    // rows of this thread:  wave*32 + lr + 8*i   (i = 0..3)
    // codes of this thread: lc + 8*j             (j = 0..15, ascending k for tie-break)
    const int rbase = wave * 32 + lr;
    const int zsw   = 4 * (lr >> 1);     // read-side swizzle: (r>>1)&3 == (lr>>1) for all i
    const int csw   = 4 * (lc >> 1);     // read-side swizzle: (r>>1)&3 == (lc>>1) for all j

    float acc[4][16];
    float zsq[4];
#pragma unroll
    for (int i = 0; i < 4; ++i) {
        zsq[i] = 0.f;
#pragma unroll
        for (int j = 0; j < 16; ++j) acc[i][j] = 0.f;
    }

    // prologue: DMA chunk 0 into buffer 0
    stage_chunk<false>(z, cb, zpad, zs[0], cs[0], rowBase, 0, wave, h4, dl);
    __syncthreads();   // drains vmcnt -> chunk 0 resident

    for (int ch = 0; ch < NCHUNK; ++ch) {
        const int b = ch & 1;

        // issue-early: DMA chunk ch+1 into the other buffer (no registers held;
        // latency hides under this chunk's compute; drained by the end barrier)
        if (ch + 1 < NCHUNK) {
            if (ch + 1 == NCHUNK - 1)
                stage_chunk<true >(z, cb, zpad, zs[b ^ 1], cs[b ^ 1], rowBase,
                                   (ch + 1) * DC, wave, h4, dl);
            else
                stage_chunk<false>(z, cb, zpad, zs[b ^ 1], cs[b ^ 1], rowBase,
                                   (ch + 1) * DC, wave, h4, dl);
        }

        // compute current chunk from LDS (arithmetic bit-identical to the passing
        // round-2 kernel: per (row,code) the fma chain runs d ascending in x,y,z,w
        // order; a swizzled float4 read returns elements d = dd..dd+3 in order;
        // tail zeros are staged -> fma identity)
        const float* zbuf = zs[b];
        const float* cbuf = cs[b];
#pragma unroll
        for (int dd = 0; dd < DC; dd += 4) {
            float4 zv[4];
#pragma unroll
            for (int i = 0; i < 4; ++i)
                zv[i] = *(const float4*)&zbuf[(rbase + 8 * i) * DC + (dd ^ zsw)];
            // z_sq accumulated with the same chain structure as the dots
#pragma unroll
            for (int i = 0; i < 4; ++i) {
                zsq[i] = fmaf(zv[i].x, zv[i].x, zsq[i]);
                zsq[i] = fmaf(zv[i].y, zv[i].y, zsq[i]);
                zsq[i] = fmaf(zv[i].z, zv[i].z, zsq[i]);
                zsq[i] = fmaf(zv[i].w, zv[i].w, zsq[i]);
            }
#pragma unroll
            for (int j = 0; j < 16; ++j) {
                float4 cv = *(const float4*)&cbuf[(lc + 8 * j) * DC + (dd ^ csw)];
#pragma unroll
                for (int i = 0; i < 4; ++i) {
                    acc[i][j] = fmaf(zv[i].x, cv.x, acc[i][j]);
                    acc[i][j] = fmaf(zv[i].y, cv.y, acc[i][j]);
                    acc[i][j] = fmaf(zv[i].z, cv.z, acc[i][j]);
                    acc[i][j] = fmaf(zv[i].w, cv.w, acc[i][j]);
                }
            }
        }

        __syncthreads();   // single barrier per chunk: drains DMA + releases buffers
    }

    // argmin epilogue — replicate np's rounding sequence:
    //   t = fp32(z_sq - 2*dot)  (2*dot exact);  dist = fp32(t + c_sq)
#pragma unroll
    for (int i = 0; i < 4; ++i) {
        float bd = 3.0e38f;
        int   bk = 0;
#pragma unroll
        for (int j = 0; j < 16; ++j) {
            int k = lc + 8 * j;
            float t    = zsq[i] - 2.0f * acc[i][j];
            float dist = t + csq[k];
            if (dist < bd) { bd = dist; bk = k; }   // strict <: first (lowest k) wins
        }
#pragma unroll
        for (int m = 1; m < 8; m <<= 1) {
            float od = __shfl_xor(bd, m);
            int   ok = __shfl_xor(bk, m);
            if (od < bd || (od == bd && ok < bk)) { bd = od; bk = ok; }
        }
        if (lc == 0) kbest[rbase + 8 * i] = bk;
    }
    __syncthreads();

    // gather: copy winning codebook rows to out (float2, rows are 8B-aligned)
    for (int r = wave; r < BROWS; r += 4) {
        int k = kbest[r];
        const float2* src = (const float2*)(cb + (long)k * DIM);
        float2* dst = (float2*)(out + (rowBase + r) * DIM);
        for (int d2 = lane; d2 < DIM / 2; d2 += 64) dst[d2] = src[d2];
    }
}

extern "C" void kernel_launch(void* const* d_in, const int* in_sizes, int n_in,
                              void* d_out, int out_size, void* d_ws, size_t ws_size,
                              hipStream_t stream) {
    const float* z  = (const float*)d_in[0];
    const float* cb = (const float*)d_in[1];
    float* out  = (float*)d_out;
    float* csq  = (float*)d_ws;             // 128 floats
    float* zpad = (float*)d_ws + KCODES;    // 32 zero floats (DMA tail source)

    csq_kernel<<<KCODES, 64, 0, stream>>>(cb, csq, zpad);
    vq_kernel<<<N_ROWS / BROWS, 256, 0, stream>>>(z, cb, csq, zpad, out);
}